// Round 4
// baseline (517.423 us; speedup 1.0000x reference)
//
#include <hip/hip_runtime.h>
#include <stdint.h>

#define CDIM 128
#define NNODES 100000
#define E0EDGES 300000
#define ELEDGES 80000

typedef unsigned short u16;
typedef unsigned int u32;
typedef short bf16x8 __attribute__((ext_vector_type(8)));
typedef float f32x4 __attribute__((ext_vector_type(4)));

__device__ __forceinline__ float bf2f(u32 u){
  union { u32 i; float f; } v; v.i = u << 16; return v.f;
}
__device__ __forceinline__ float bf2f_hi(u32 u){
  union { u32 i; float f; } v; v.i = u & 0xffff0000u; return v.f;
}
__device__ __forceinline__ u16 f2bf(float f){
  u32 u = __builtin_bit_cast(u32, f);
  u32 r = (u + 0x7fffu + ((u >> 16) & 1u)) >> 16;
  return (u16)r;
}
__device__ __forceinline__ u32 pack2(float lo, float hi){
  return ((u32)f2bf(hi) << 16) | (u32)f2bf(lo);
}
// HW packed f32->bf16 (RNE), 1 instr for 2 elements
__device__ __forceinline__ u32 cvtpk(float lo, float hi){
  u32 r;
  asm("v_cvt_pk_bf16_f32 %0, %1, %2" : "=v"(r) : "v"(lo), "v"(hi));
  return r;
}
// DPP cross-lane move (0-fill at 16-lane-row boundary) — validated in R3
template<int CTRL>
__device__ __forceinline__ float dppf(float v){
  int r = __builtin_amdgcn_update_dpp(0, __builtin_bit_cast(int, v), CTRL, 0xF, 0xF, true);
  return __builtin_bit_cast(float, r);
}
#define DPP_SHR1 0x111   // lane l <- l-1 (within 16-lane row)
#define DPP_SHL1 0x101   // lane l <- l+1
#define DPP_XOR1 0xB1    // quad_perm [1,0,3,2]
#define DPP_XOR2 0x4E    // quad_perm [2,3,0,1]

// element index of swizzled [rows][128] bf16 LDS tile (16B-granule XOR swizzle)
__device__ __forceinline__ int swzi(int r, int c){
  return r*CDIM + ((((c>>3) ^ (r&7)))<<3) + (c&7);
}
// index of a 4-col group (col0 multiple of 4, stays within one 8-col granule)
__device__ __forceinline__ int swz8(int r, int col0){
  int chunk = col0 >> 3;
  return r*CDIM + ((chunk ^ (r & 7)) << 3) + (col0 & 7);
}

// ---- 64x64 register-tiled gemm: wave computes act-rows [rowbase..+63] x feats [featbase..+63]
// acc[a][b][q] = out(feature = featbase+16b+g*4+q, act_row = rowbase+16a+lr)
__device__ __forceinline__ void gemm4(const u16* W, const u16* A, f32x4 acc[4][4],
                                      int rowbase, int featbase, int lr, int g){
#pragma unroll
  for (int ks = 0; ks < 4; ++ks){
    const int ch = ks*4 + g;
    const int sch = (ch ^ (lr & 7)) << 3;     // row&7 == lr&7 for all frags (bases %64==0)
    bf16x8 af[4], wf[4];
#pragma unroll
    for (int a = 0; a < 4; ++a){
      const int r = rowbase + 16*a + lr;
      af[a] = *(const bf16x8*)&A[r*CDIM + sch];
    }
#pragma unroll
    for (int b = 0; b < 4; ++b){
      const int wr = featbase + 16*b + lr;
      wf[b] = *(const bf16x8*)&W[wr*CDIM + sch];
    }
#pragma unroll
    for (int a = 0; a < 4; ++a)
#pragma unroll
      for (int b = 0; b < 4; ++b)
        acc[a][b] = __builtin_amdgcn_mfma_f32_16x16x32_bf16(wf[b], af[a], acc[a][b], 0, 0, 0);
  }
}

// ---- legacy 16-row gemm (final_kernel): acc(row = g*4+q, col = ct*16+lr)
__device__ __forceinline__ void gemm64(const u16* A, const u16* B, f32x4* acc, int wave, int lane){
  const int lr = lane & 15, g = lane >> 4;
  const int arow = wave*16 + lr;
#pragma unroll
  for (int ks = 0; ks < 4; ++ks){
    const int ach = ks*4 + g;
    bf16x8 a = *(const bf16x8*)&A[arow*CDIM + ((ach ^ (arow & 7)) << 3)];
#pragma unroll
    for (int ct = 0; ct < 8; ++ct){
      const int brow = ct*16 + lr;
      bf16x8 b = *(const bf16x8*)&B[brow*CDIM + ((ach ^ (brow & 7)) << 3)];
      acc[ct] = __builtin_amdgcn_mfma_f32_16x16x32_bf16(a, b, acc[ct], 0, 0, 0);
    }
  }
}

// stage a [128][128] bf16 (B^T row-major) matrix into swizzled LDS (256 threads)
__device__ __forceinline__ void stage_w(const u16* __restrict__ gsrc, u16* sdst, int tid){
  for (int c = tid; c < CDIM*16; c += 256){
    int r = c >> 4, ch = c & 15;
    *(uint4*)&sdst[(r*16 + (ch ^ (r & 7)))*8] = ((const uint4*)(gsrc + r*CDIM))[ch];
  }
}

// ---------------- prep: f32->bf16 transpose weights to B^T + eWt = emb@Wt_bot + bt (f32)
__global__ __launch_bounds__(256) void prep_kernel(
    const float* __restrict__ Wt, const float* __restrict__ w0, const float* __restrict__ w1,
    const float* __restrict__ fw0, const float* __restrict__ fw1,
    const float* __restrict__ emb, const float* __restrict__ bt,
    u16* __restrict__ WtT, u16* __restrict__ w0T, u16* __restrict__ w1T,
    u16* __restrict__ fw0T, u16* __restrict__ fw1T, float* __restrict__ eWt)
{
  int tid = blockIdx.x*blockDim.x + threadIdx.x;
  int nt = gridDim.x*blockDim.x;
  for (int idx = tid; idx < 3*CDIM*CDIM; idx += nt){
    int i = idx/(CDIM*CDIM), rem = idx%(CDIM*CDIM), col = rem/CDIM, k = rem%CDIM;
    WtT[idx] = f2bf(Wt[(size_t)i*2*CDIM*CDIM + k*CDIM + col]);   // top half of Wt
    w0T[idx] = f2bf(w0[(size_t)i*CDIM*CDIM + k*CDIM + col]);
    w1T[idx] = f2bf(w1[(size_t)i*CDIM*CDIM + k*CDIM + col]);
  }
  for (int idx = tid; idx < CDIM*CDIM; idx += nt){
    int col = idx/CDIM, k = idx%CDIM;
    fw0T[idx] = f2bf(fw0[k*CDIM + col]);
    fw1T[idx] = f2bf(fw1[k*CDIM + col]);
  }
  for (int idx = tid; idx < 3*3*CDIM; idx += nt){
    int i = idx/(3*CDIM), a = (idx/CDIM)%3, c2 = idx%CDIM;
    float s = bt[i*CDIM + c2];
    for (int k = 0; k < CDIM; ++k)
      s += emb[(i*3 + a)*CDIM + k] * Wt[(size_t)i*2*CDIM*CDIM + (CDIM + k)*CDIM + c2];
    eWt[idx] = s;
  }
}

// ---------------- aux: xb = bf16(x)  +  4 CSR rowptrs (merged launches)
__global__ __launch_bounds__(256) void aux_kernel(
    const float* __restrict__ x, u16* __restrict__ xb,
    const int* __restrict__ n0, const int* __restrict__ n1,
    const int* __restrict__ n2, const int* __restrict__ n3,
    int* __restrict__ rp0, int* __restrict__ rp1,
    int* __restrict__ rp2, int* __restrict__ rp3)
{
  const int XBQ = NNODES*CDIM/4;
  int gtid = blockIdx.x*256 + threadIdx.x;
  if (gtid < XBQ){
    size_t idx = (size_t)gtid*4;
    float4 v = *(const float4*)(x + idx);
    uint2 o; o.x = cvtpk(v.x, v.y); o.y = cvtpk(v.z, v.w);
    *(uint2*)(xb + idx) = o;
    return;
  }
  int t = gtid - XBQ;
  const int* tgt; int ne; int* rowptr;
  if (t < E0EDGES){ tgt = n0; ne = E0EDGES; rowptr = rp0; }
  else {
    t -= E0EDGES;
    if (t < ELEDGES){ tgt = n1; ne = ELEDGES; rowptr = rp1; }
    else {
      t -= ELEDGES;
      if (t < ELEDGES){ tgt = n2; ne = ELEDGES; rowptr = rp2; }
      else {
        t -= ELEDGES;
        if (t < ELEDGES){ tgt = n3; ne = ELEDGES; rowptr = rp3; }
        else return;
      }
    }
  }
  int e = t;
  int tc = tgt[e];
  int tp = (e == 0) ? -1 : tgt[e-1];
  for (int n = tp + 1; n <= tc; ++n) rowptr[n] = e;
  if (e == ne - 1){
    for (int n = tc + 1; n <= NNODES; ++n) rowptr[n] = ne;
  }
}

// ---------------- layer kernel: 256 threads / 4 waves, 128 rows, wave-tile 64x64
template<int L>
__global__ __launch_bounds__(256, 2) void layer_kernel(
    const u16* __restrict__ xb,
    const int* __restrict__ nl,      // (L+2, EL)
    const int* __restrict__ ai,      // (L+2, EL)
    const u16* __restrict__ WtT, const u16* __restrict__ w0T, const u16* __restrict__ w1T,
    const float* __restrict__ eWt,   // (3,3,128) f32
    const float* __restrict__ b0g, const float* __restrict__ b1g,
    const float* __restrict__ cepsg,
    u16* __restrict__ oL)            // (EL, 128) bf16
{
  constexpr int RPE = (L == 1) ? 2 : 4;
  constexpr int TE  = 128 / RPE;
  constexpr int LI  = L - 1;
  __shared__ __align__(16) u16 sW[CDIM*CDIM];     // 32 KB weights
  __shared__ __align__(16) u16 sA[128*CDIM];      // 32 KB activations
  __shared__ __align__(16) float sE[3*136];
  __shared__ __align__(16) float b0s[CDIM];
  __shared__ __align__(16) float b1s[CDIM];
  __shared__ int sAid[128];

  const int tid  = threadIdx.x;
  const int wave = tid >> 6, lane = tid & 63;
  const int lr   = lane & 15, g = lane >> 4;
  const int wr   = wave >> 1, wc = wave & 1;
  const int rowbase  = wr*64;
  const int featbase = wc*64;
  const int e0   = blockIdx.x * TE;
  const int pos  = lr & (RPE - 1);                // row%RPE == lr%RPE (bases %RPE==0)
  const float mu = (pos > 0) ? 1.f : 0.f;
  const float md = (pos < L) ? 1.f : 0.f;
  const float mz = (L == 2 && pos == 3) ? 0.f : 1.f;
  const float ce = 1.0f + cepsg[LI];

  // stage Wt + tables
  stage_w(WtT + LI*CDIM*CDIM, sW, tid);
  for (int c = tid; c < 3*CDIM; c += 256) sE[(c>>7)*136 + (c&127)] = eWt[LI*3*CDIM + c];
  if (tid < CDIM) b0s[tid] = b0g[LI*CDIM + tid];
  else if (tid < 2*CDIM) b1s[tid-CDIM] = b1g[LI*CDIM + (tid-CDIM)];
  if (tid < 128){
    int p = tid & (RPE - 1);
    sAid[tid] = (p <= L) ? ai[(1 + p)*ELEDGES + e0 + tid/RPE] : 0;
  }
  // gather rows -> sA (block-cooperative, bf16 source)
  for (int c = tid; c < 128*16; c += 256){
    int r = c >> 4, ch = c & 15;
    int p = r & (RPE - 1);
    uint4 v = make_uint4(0u,0u,0u,0u);
    if (p <= L){
      int node = nl[(1 + p)*ELEDGES + e0 + r/RPE];
      v = ((const uint4*)(xb + (size_t)node*CDIM))[ch];
    }
    *(uint4*)&sA[(r*16 + (ch ^ (r & 7)))*8] = v;
  }
  // prefetch w0 into regs (latency hides under GEMM1)
  uint4 wpre[8];
#pragma unroll
  for (int i = 0; i < 8; ++i){
    int c = tid + i*256;
    wpre[i] = ((const uint4*)(w0T + LI*CDIM*CDIM + (c>>4)*CDIM))[c & 15];
  }
  __syncthreads();                                 // B1: sW/sA/sE/sAid ready

  f32x4 acc[4][4];
#pragma unroll
  for (int a = 0; a < 4; ++a)
#pragma unroll
    for (int b = 0; b < 4; ++b) acc[a][b] = (f32x4){0.f,0.f,0.f,0.f};
  gemm4(sW, sA, acc, rowbase, featbase, lr, g);    // GEMM1: cc @ Wt_top
  __syncthreads();                                 // B2: sW & sA(cc) reads complete

  // write w0 from prefetched regs
#pragma unroll
  for (int i = 0; i < 8; ++i){
    int c = tid + i*256;
    int r = c >> 4, ch = c & 15;
    *(uint4*)&sW[(r*16 + (ch ^ (r & 7)))*8] = wpre[i];
  }
  // ep1: h = acc + eWt[aid]; z = ce*cc + h[row-1] + h[row+1]  (DPP stencil)
#pragma unroll
  for (int a = 0; a < 4; ++a){
    const int r = rowbase + 16*a + lr;
    const float* eWrow = &sE[sAid[r]*136];
#pragma unroll
    for (int b = 0; b < 4; ++b){
      const int col0 = featbase + 16*b + g*4;
      float4 ew = *(const float4*)&eWrow[col0];
      float h0 = acc[a][b][0] + ew.x;
      float h1 = acc[a][b][1] + ew.y;
      float h2 = acc[a][b][2] + ew.z;
      float h3 = acc[a][b][3] + ew.w;
      float u0 = dppf<DPP_SHR1>(h0), u1 = dppf<DPP_SHR1>(h1),
            u2 = dppf<DPP_SHR1>(h2), u3 = dppf<DPP_SHR1>(h3);
      float d0 = dppf<DPP_SHL1>(h0), d1 = dppf<DPP_SHL1>(h1),
            d2 = dppf<DPP_SHL1>(h2), d3 = dppf<DPP_SHL1>(h3);
      uint2 ccv = *(const uint2*)&sA[swz8(r, col0)];
      float c0 = bf2f(ccv.x & 0xffffu), c1 = bf2f_hi(ccv.x);
      float c2 = bf2f(ccv.y & 0xffffu), c3 = bf2f_hi(ccv.y);
      uint2 zv;
      zv.x = cvtpk(ce*c0 + mu*u0 + md*d0, ce*c1 + mu*u1 + md*d1);
      zv.y = cvtpk(ce*c2 + mu*u2 + md*d2, ce*c3 + mu*u3 + md*d3);
      *(uint2*)&sA[swz8(r, col0)] = zv;
    }
  }
  __syncthreads();                                 // B3: w0 + z ready

#pragma unroll
  for (int a = 0; a < 4; ++a)
#pragma unroll
    for (int b = 0; b < 4; ++b) acc[a][b] = (f32x4){0.f,0.f,0.f,0.f};
  // prefetch w1 (hides under GEMM2)
#pragma unroll
  for (int i = 0; i < 8; ++i){
    int c = tid + i*256;
    wpre[i] = ((const uint4*)(w1T + LI*CDIM*CDIM + (c>>4)*CDIM))[c & 15];
  }
  gemm4(sW, sA, acc, rowbase, featbase, lr, g);    // GEMM2: z @ w0
  __syncthreads();                                 // B4: sW & sA(z) reads complete

#pragma unroll
  for (int i = 0; i < 8; ++i){
    int c = tid + i*256;
    int r = c >> 4, ch = c & 15;
    *(uint4*)&sW[(r*16 + (ch ^ (r & 7)))*8] = wpre[i];
  }
  // ep2: t = relu(acc + b0) -> sA
#pragma unroll
  for (int a = 0; a < 4; ++a){
    const int r = rowbase + 16*a + lr;
#pragma unroll
    for (int b = 0; b < 4; ++b){
      const int col0 = featbase + 16*b + g*4;
      float4 bb = *(const float4*)&b0s[col0];
      float t0 = acc[a][b][0] + bb.x; t0 = t0 > 0.f ? t0 : 0.f;
      float t1 = acc[a][b][1] + bb.y; t1 = t1 > 0.f ? t1 : 0.f;
      float t2 = acc[a][b][2] + bb.z; t2 = t2 > 0.f ? t2 : 0.f;
      float t3 = acc[a][b][3] + bb.w; t3 = t3 > 0.f ? t3 : 0.f;
      uint2 tv; tv.x = cvtpk(t0, t1); tv.y = cvtpk(t2, t3);
      *(uint2*)&sA[swz8(r, col0)] = tv;
    }
  }
  __syncthreads();                                 // B5: w1 + t ready

#pragma unroll
  for (int a = 0; a < 4; ++a)
#pragma unroll
    for (int b = 0; b < 4; ++b) acc[a][b] = (f32x4){0.f,0.f,0.f,0.f};
  gemm4(sW, sA, acc, rowbase, featbase, lr, g);    // GEMM3: t @ w1

  // ep3: per-edge sum over positions (DPP quad reduce) + (L+1)*b1, store bf16
  const float nb = (float)(L + 1);
#pragma unroll
  for (int a = 0; a < 4; ++a){
    const int r = rowbase + 16*a + lr;
    const int ed = e0 + r/RPE;
#pragma unroll
    for (int b = 0; b < 4; ++b){
      float v0 = mz*acc[a][b][0], v1 = mz*acc[a][b][1],
            v2 = mz*acc[a][b][2], v3 = mz*acc[a][b][3];
      v0 += dppf<DPP_XOR1>(v0); v1 += dppf<DPP_XOR1>(v1);
      v2 += dppf<DPP_XOR1>(v2); v3 += dppf<DPP_XOR1>(v3);
      if constexpr (RPE == 4){
        v0 += dppf<DPP_XOR2>(v0); v1 += dppf<DPP_XOR2>(v1);
        v2 += dppf<DPP_XOR2>(v2); v3 += dppf<DPP_XOR2>(v3);
      }
      if (pos == 0){
        const int col0 = featbase + 16*b + g*4;
        float4 bb = *(const float4*)&b1s[col0];
        uint2 ov;
        ov.x = cvtpk(v0 + nb*bb.x, v1 + nb*bb.y);
        ov.y = cvtpk(v2 + nb*bb.z, v3 + nb*bb.w);
        *(uint2*)(oL + (size_t)ed*CDIM + col0) = ov;
      }
    }
  }
}

// ---------------- per-node gather: rc = (1+r0)*seg0 + sum_L (1+rL)*segL  (bf16 out)
__global__ __launch_bounds__(256) void gather_rc_kernel(
    const float* __restrict__ x, const u16* __restrict__ xbopt,
    const int* __restrict__ s0,
    const int* __restrict__ rp0, const int* __restrict__ rp1,
    const int* __restrict__ rp2, const int* __restrict__ rp3,
    const u16* __restrict__ o1, const u16* __restrict__ o2, const u16* __restrict__ o3,
    const float* __restrict__ repsg, u16* __restrict__ rcb)
{
  const int wave = threadIdx.x >> 6, lane = threadIdx.x & 63;
  const int node = blockIdx.x*4 + wave;
  if (node >= NNODES) return;
  float a0 = 0.f, a1 = 0.f;
  {
    const float sc = 1.f + repsg[0];
    int lo = rp0[node], hi = rp0[node+1];
    if (xbopt){
      for (int e = lo; e < hi; ++e){
        int s = s0[e];
        u32 v = *(const u32*)(xbopt + (size_t)s*CDIM + lane*2);
        a0 += sc*bf2f(v & 0xffffu); a1 += sc*bf2f_hi(v);
      }
    } else {
      for (int e = lo; e < hi; ++e){
        int s = s0[e];
        float2 v = *(const float2*)(x + (size_t)s*CDIM + lane*2);
        a0 += sc*v.x; a1 += sc*v.y;
      }
    }
  }
  const u16* os[3]  = {o1, o2, o3};
  const int* rps[3] = {rp1, rp2, rp3};
#pragma unroll
  for (int li = 0; li < 3; ++li){
    const float sc = 1.f + repsg[1+li];
    int lo = rps[li][node], hi = rps[li][node+1];
    for (int e = lo; e < hi; ++e){
      u32 v = *(const u32*)(os[li] + (size_t)e*CDIM + lane*2);
      a0 += sc*bf2f(v & 0xffffu); a1 += sc*bf2f_hi(v);
    }
  }
  *(u32*)(rcb + (size_t)node*CDIM + lane*2) = pack2(a0, a1);
}

// ---------------- final: out = mlp2((1+eps)*x + rc, fin_*)  (f32 out)
__global__ __launch_bounds__(256) void final_kernel(
    const float* __restrict__ x, const u16* __restrict__ rc,
    const u16* __restrict__ fw0T, const u16* __restrict__ fw1T,
    const float* __restrict__ fb0, const float* __restrict__ fb1,
    const float* __restrict__ epsg, float* __restrict__ outp)
{
  __shared__ __align__(16) u16 sW[CDIM*CDIM];
  __shared__ __align__(16) u16 sA[64*CDIM];
  const int tid  = threadIdx.x;
  const int wave = tid >> 6, lane = tid & 63;
  const int lr   = lane & 15, g = lane >> 4;
  const int r0   = blockIdx.x * 64;
  const float se = 1.0f + epsg[0];

  stage_w(fw0T, sW, tid);
  for (int c = tid; c < 64*16; c += 256){
    int r = c >> 4, ch = c & 15;
    int node = r0 + r;
    uint4 v = make_uint4(0,0,0,0);
    if (node < NNODES){
      const float4* px = (const float4*)(x + (size_t)node*CDIM + ch*8);
      float4 fa = px[0], fb = px[1];
      const u32* pr = (const u32*)(rc + (size_t)node*CDIM + ch*8);
      u32 r0v = pr[0], r1v = pr[1], r2v = pr[2], r3v = pr[3];
      v.x = pack2(se*fa.x + bf2f(r0v & 0xffffu), se*fa.y + bf2f_hi(r0v));
      v.y = pack2(se*fa.z + bf2f(r1v & 0xffffu), se*fa.w + bf2f_hi(r1v));
      v.z = pack2(se*fb.x + bf2f(r2v & 0xffffu), se*fb.y + bf2f_hi(r2v));
      v.w = pack2(se*fb.z + bf2f(r3v & 0xffffu), se*fb.w + bf2f_hi(r3v));
    }
    *(uint4*)&sA[(r*16 + (ch ^ (r & 7)))*8] = v;
  }
  __syncthreads();

  f32x4 acc[8];
#pragma unroll
  for (int ct = 0; ct < 8; ++ct) acc[ct] = (f32x4){0.f,0.f,0.f,0.f};
  gemm64(sA, sW, acc, wave, lane);
  __syncthreads();
#pragma unroll
  for (int ct = 0; ct < 8; ++ct){
    const int col = ct*16 + lr;
    const float bb = fb0[col];
#pragma unroll
    for (int q = 0; q < 4; ++q){
      const int r = wave*16 + g*4 + q;
      float t = acc[ct][q] + bb;
      t = t > 0.f ? t : 0.f;
      sA[swzi(r, col)] = f2bf(t);
    }
  }
  stage_w(fw1T, sW, tid);
  __syncthreads();
#pragma unroll
  for (int ct = 0; ct < 8; ++ct) acc[ct] = (f32x4){0.f,0.f,0.f,0.f};
  gemm64(sA, sW, acc, wave, lane);
#pragma unroll
  for (int ct = 0; ct < 8; ++ct){
    const int col = ct*16 + lr;
    const float bb = fb1[col];
#pragma unroll
    for (int q = 0; q < 4; ++q){
      const int r = wave*16 + g*4 + q;
      int node = r0 + r;
      if (node < NNODES) outp[(size_t)node*CDIM + col] = acc[ct][q] + bb;
    }
  }
}

extern "C" void kernel_launch(void* const* d_in, const int* in_sizes, int n_in,
                              void* d_out, int out_size, void* d_ws, size_t ws_size,
                              hipStream_t stream)
{
  const float* x   = (const float*)d_in[0];
  const int* n0    = (const int*)d_in[1];
  const int* n1    = (const int*)d_in[2];
  const int* a1    = (const int*)d_in[3];
  const int* n2    = (const int*)d_in[4];
  const int* a2    = (const int*)d_in[5];
  const int* n3    = (const int*)d_in[6];
  const int* a3    = (const int*)d_in[7];
  const float* emb = (const float*)d_in[8];
  const float* Wt  = (const float*)d_in[9];
  const float* bt  = (const float*)d_in[10];
  const float* w0  = (const float*)d_in[11];
  const float* b0  = (const float*)d_in[12];
  const float* w1  = (const float*)d_in[13];
  const float* b1  = (const float*)d_in[14];
  const float* ceps= (const float*)d_in[15];
  const float* reps= (const float*)d_in[16];
  const float* eps = (const float*)d_in[17];
  const float* fw0 = (const float*)d_in[18];
  const float* fb0 = (const float*)d_in[19];
  const float* fw1 = (const float*)d_in[20];
  const float* fb1 = (const float*)d_in[21];
  float* outp = (float*)d_out;

  char* w = (char*)d_ws;
  size_t off = 0;
  auto alloc = [&](size_t bytes) -> char* {
    char* p = w + off;
    off += (bytes + 255) & ~((size_t)255);
    return p;
  };
  u16* o1   = (u16*)alloc((size_t)ELEDGES*CDIM*2);
  u16* o2   = (u16*)alloc((size_t)ELEDGES*CDIM*2);
  u16* o3   = (u16*)alloc((size_t)ELEDGES*CDIM*2);
  u16* rcb  = (u16*)alloc((size_t)NNODES*CDIM*2);
  int* rp0  = (int*)alloc((size_t)(NNODES+1)*4);
  int* rp1  = (int*)alloc((size_t)(NNODES+1)*4);
  int* rp2  = (int*)alloc((size_t)(NNODES+1)*4);
  int* rp3  = (int*)alloc((size_t)(NNODES+1)*4);
  u16* WtT  = (u16*)alloc((size_t)3*CDIM*CDIM*2);
  u16* w0T  = (u16*)alloc((size_t)3*CDIM*CDIM*2);
  u16* w1T  = (u16*)alloc((size_t)3*CDIM*CDIM*2);
  u16* fw0T = (u16*)alloc((size_t)CDIM*CDIM*2);
  u16* fw1T = (u16*)alloc((size_t)CDIM*CDIM*2);
  float* eWt = (float*)alloc((size_t)3*3*CDIM*4);
  // xb: separate allocation if ws permits (keeps xb alive for gather_rc);
  // else alias rcb (layer kernels consume xb before gather_rc writes rcb).
  const size_t xbbytes = (size_t)NNODES*CDIM*2;
  u16* xb; const u16* xbopt;
  if (off + xbbytes <= ws_size){ xb = (u16*)alloc(xbbytes); xbopt = xb; }
  else { xb = rcb; xbopt = nullptr; }
  (void)in_sizes; (void)n_in; (void)out_size;

  prep_kernel<<<192, 256, 0, stream>>>(Wt, w0, w1, fw0, fw1, emb, bt,
                                       WtT, w0T, w1T, fw0T, fw1T, eWt);
  {
    const int XBQ = NNODES*CDIM/4;
    int total = XBQ + E0EDGES + 3*ELEDGES;
    aux_kernel<<<(total + 255)/256, 256, 0, stream>>>(x, xb, n0, n1, n2, n3,
                                                      rp0, rp1, rp2, rp3);
  }

  layer_kernel<1><<<ELEDGES/64, 256, 0, stream>>>(xb, n1, a1, WtT, w0T, w1T, eWt, b0, b1, ceps, o1);
  layer_kernel<2><<<ELEDGES/32, 256, 0, stream>>>(xb, n2, a2, WtT, w0T, w1T, eWt, b0, b1, ceps, o2);
  layer_kernel<3><<<ELEDGES/32, 256, 0, stream>>>(xb, n3, a3, WtT, w0T, w1T, eWt, b0, b1, ceps, o3);

  gather_rc_kernel<<<(NNODES+3)/4, 256, 0, stream>>>(x, xbopt, n0 + E0EDGES, rp0, rp1, rp2, rp3,
                                                     o1, o2, o3, reps, rcb);
  final_kernel<<<(NNODES+63)/64, 256, 0, stream>>>(x, rcb, fw0T, fw1T, fb0, fb1, eps, outp);
}

// Round 5
// 392.971 us; speedup vs baseline: 1.3167x; 1.3167x over previous
//
#include <hip/hip_runtime.h>
#include <stdint.h>

#define CDIM 128
#define NNODES 100000
#define E0EDGES 300000
#define ELEDGES 80000

typedef unsigned short u16;
typedef unsigned int u32;
typedef short bf16x8 __attribute__((ext_vector_type(8)));
typedef float f32x4 __attribute__((ext_vector_type(4)));

__device__ __forceinline__ float bf2f(u32 u){
  union { u32 i; float f; } v; v.i = u << 16; return v.f;
}
__device__ __forceinline__ float bf2f_hi(u32 u){
  union { u32 i; float f; } v; v.i = u & 0xffff0000u; return v.f;
}
__device__ __forceinline__ u16 f2bf(float f){
  u32 u = __builtin_bit_cast(u32, f);
  u32 r = (u + 0x7fffu + ((u >> 16) & 1u)) >> 16;
  return (u16)r;
}
__device__ __forceinline__ u32 pack2(float lo, float hi){
  return ((u32)f2bf(hi) << 16) | (u32)f2bf(lo);
}
__device__ __forceinline__ u32 cvtpk(float lo, float hi){
  u32 r;
  asm("v_cvt_pk_bf16_f32 %0, %1, %2" : "=v"(r) : "v"(lo), "v"(hi));
  return r;
}
template<int CTRL>
__device__ __forceinline__ float dppf(float v){
  int r = __builtin_amdgcn_update_dpp(0, __builtin_bit_cast(int, v), CTRL, 0xF, 0xF, true);
  return __builtin_bit_cast(float, r);
}
#define DPP_SHR1 0x111   // lane l <- l-1 (within 16-lane row)
#define DPP_SHL1 0x101   // lane l <- l+1
#define DPP_XOR1 0xB1    // quad_perm [1,0,3,2]
#define DPP_XOR2 0x4E    // quad_perm [2,3,0,1]

// async global->LDS, 16B per lane, linear LDS dest (base + lane*16)
__device__ __forceinline__ void gll16(const void* g, void* l){
  __builtin_amdgcn_global_load_lds(
      (const __attribute__((address_space(1))) void*)g,
      (__attribute__((address_space(3))) void*)l, 16, 0, 0);
}

// element index of swizzled [rows][128] bf16 LDS tile (16B-granule XOR swizzle)
__device__ __forceinline__ int swzi(int r, int c){
  return r*CDIM + ((((c>>3) ^ (r&7)))<<3) + (c&7);
}
// index of a 4-col group (col0 multiple of 4, stays within one 8-col granule)
__device__ __forceinline__ int swz8(int r, int col0){
  int chunk = col0 >> 3;
  return r*CDIM + ((chunk ^ (r & 7)) << 3) + (col0 & 7);
}

// ---- 32x64 register-tiled gemm: wave computes act-rows [rowbase..+31] x feats [featbase..+63]
// acc[a][b][q] = out(feature = featbase+16b+g*4+q, act_row = rowbase+16a+lr)
__device__ __forceinline__ void gemmT(const u16* W, const u16* A, f32x4 acc[2][4],
                                      int rowbase, int featbase, int lr, int g){
#pragma unroll
  for (int ks = 0; ks < 4; ++ks){
    const int sch = ((ks*4 + g) ^ (lr & 7)) << 3;   // row&7 == lr&7 (bases %16==0... %8==0)
    bf16x8 a0 = *(const bf16x8*)&A[(rowbase      + lr)*CDIM + sch];
    bf16x8 a1 = *(const bf16x8*)&A[(rowbase + 16 + lr)*CDIM + sch];
    bf16x8 w0f = *(const bf16x8*)&W[(featbase      + lr)*CDIM + sch];
    bf16x8 w1f = *(const bf16x8*)&W[(featbase + 16 + lr)*CDIM + sch];
    bf16x8 w2f = *(const bf16x8*)&W[(featbase + 32 + lr)*CDIM + sch];
    bf16x8 w3f = *(const bf16x8*)&W[(featbase + 48 + lr)*CDIM + sch];
    acc[0][0] = __builtin_amdgcn_mfma_f32_16x16x32_bf16(w0f, a0, acc[0][0], 0, 0, 0);
    acc[0][1] = __builtin_amdgcn_mfma_f32_16x16x32_bf16(w1f, a0, acc[0][1], 0, 0, 0);
    acc[0][2] = __builtin_amdgcn_mfma_f32_16x16x32_bf16(w2f, a0, acc[0][2], 0, 0, 0);
    acc[0][3] = __builtin_amdgcn_mfma_f32_16x16x32_bf16(w3f, a0, acc[0][3], 0, 0, 0);
    acc[1][0] = __builtin_amdgcn_mfma_f32_16x16x32_bf16(w0f, a1, acc[1][0], 0, 0, 0);
    acc[1][1] = __builtin_amdgcn_mfma_f32_16x16x32_bf16(w1f, a1, acc[1][1], 0, 0, 0);
    acc[1][2] = __builtin_amdgcn_mfma_f32_16x16x32_bf16(w2f, a1, acc[1][2], 0, 0, 0);
    acc[1][3] = __builtin_amdgcn_mfma_f32_16x16x32_bf16(w3f, a1, acc[1][3], 0, 0, 0);
  }
}

// ---- legacy 16-row gemm (final_kernel): acc(row = g*4+q, col = ct*16+lr)
__device__ __forceinline__ void gemm64(const u16* A, const u16* B, f32x4* acc, int wave, int lane){
  const int lr = lane & 15, g = lane >> 4;
  const int arow = wave*16 + lr;
#pragma unroll
  for (int ks = 0; ks < 4; ++ks){
    const int ach = ks*4 + g;
    bf16x8 a = *(const bf16x8*)&A[arow*CDIM + ((ach ^ (arow & 7)) << 3)];
#pragma unroll
    for (int ct = 0; ct < 8; ++ct){
      const int brow = ct*16 + lr;
      bf16x8 b = *(const bf16x8*)&B[brow*CDIM + ((ach ^ (brow & 7)) << 3)];
      acc[ct] = __builtin_amdgcn_mfma_f32_16x16x32_bf16(a, b, acc[ct], 0, 0, 0);
    }
  }
}

// stage a [128][128] bf16 (B^T row-major) matrix into swizzled LDS (256 threads)
__device__ __forceinline__ void stage_w(const u16* __restrict__ gsrc, u16* sdst, int tid){
  for (int c = tid; c < CDIM*16; c += 256){
    int r = c >> 4, ch = c & 15;
    *(uint4*)&sdst[(r*16 + (ch ^ (r & 7)))*8] = ((const uint4*)(gsrc + r*CDIM))[ch];
  }
}

// ---------------- prep: layer weights -> PRE-SWIZZLED bf16 (linear DMA reproduces the
// swizzled LDS layout); final weights -> plain B^T; eWt = emb@Wt_bot + bt (f32)
__global__ __launch_bounds__(256) void prep_kernel(
    const float* __restrict__ Wt, const float* __restrict__ w0, const float* __restrict__ w1,
    const float* __restrict__ fw0, const float* __restrict__ fw1,
    const float* __restrict__ emb, const float* __restrict__ bt,
    u16* __restrict__ WtS, u16* __restrict__ w0S, u16* __restrict__ w1S,
    u16* __restrict__ fw0T, u16* __restrict__ fw1T, float* __restrict__ eWt)
{
  int tid = blockIdx.x*blockDim.x + threadIdx.x;
  int nt = gridDim.x*blockDim.x;
  // swizzled store: halfword s -> holds W^T[r][k] with r=s>>7, ch=((s>>3)&15)^(r&7), k=ch*8+(s&7)
  for (int idx = tid; idx < 3*CDIM*CDIM; idx += nt){
    int i = idx >> 14, s = idx & 16383;
    int r = s >> 7, ch = ((s >> 3) & 15) ^ (r & 7), k = ch*8 + (s & 7);
    WtS[idx] = f2bf(Wt[(size_t)i*2*CDIM*CDIM + k*CDIM + r]);   // top half of Wt
    w0S[idx] = f2bf(w0[(size_t)i*CDIM*CDIM + k*CDIM + r]);
    w1S[idx] = f2bf(w1[(size_t)i*CDIM*CDIM + k*CDIM + r]);
  }
  for (int idx = tid; idx < CDIM*CDIM; idx += nt){
    int col = idx/CDIM, k = idx%CDIM;
    fw0T[idx] = f2bf(fw0[k*CDIM + col]);
    fw1T[idx] = f2bf(fw1[k*CDIM + col]);
  }
  for (int idx = tid; idx < 3*3*CDIM; idx += nt){
    int i = idx/(3*CDIM), a = (idx/CDIM)%3, c2 = idx%CDIM;
    float s = bt[i*CDIM + c2];
    for (int k = 0; k < CDIM; ++k)
      s += emb[(i*3 + a)*CDIM + k] * Wt[(size_t)i*2*CDIM*CDIM + (CDIM + k)*CDIM + c2];
    eWt[idx] = s;
  }
}

// ---------------- aux: xb = bf16(x)  +  4 CSR rowptrs  +  zero row (merged)
__global__ __launch_bounds__(256) void aux_kernel(
    const float* __restrict__ x, u16* __restrict__ xb,
    const int* __restrict__ n0, const int* __restrict__ n1,
    const int* __restrict__ n2, const int* __restrict__ n3,
    int* __restrict__ rp0, int* __restrict__ rp1,
    int* __restrict__ rp2, int* __restrict__ rp3,
    u16* __restrict__ zrow)
{
  const int XBQ = NNODES*CDIM/4;
  int gtid = blockIdx.x*256 + threadIdx.x;
  if (gtid < XBQ){
    size_t idx = (size_t)gtid*4;
    float4 v = *(const float4*)(x + idx);
    uint2 o; o.x = cvtpk(v.x, v.y); o.y = cvtpk(v.z, v.w);
    *(uint2*)(xb + idx) = o;
    return;
  }
  int t = gtid - XBQ;
  const int* tgt; int ne; int* rowptr;
  if (t < E0EDGES){ tgt = n0; ne = E0EDGES; rowptr = rp0; }
  else {
    t -= E0EDGES;
    if (t < ELEDGES){ tgt = n1; ne = ELEDGES; rowptr = rp1; }
    else {
      t -= ELEDGES;
      if (t < ELEDGES){ tgt = n2; ne = ELEDGES; rowptr = rp2; }
      else {
        t -= ELEDGES;
        if (t < ELEDGES){ tgt = n3; ne = ELEDGES; rowptr = rp3; }
        else {
          t -= ELEDGES;
          if (t < 64) ((u32*)zrow)[t] = 0u;   // 256B zero block for dummy-row DMA
          return;
        }
      }
    }
  }
  int e = t;
  int tc = tgt[e];
  int tp = (e == 0) ? -1 : tgt[e-1];
  for (int n = tp + 1; n <= tc; ++n) rowptr[n] = e;
  if (e == ne - 1){
    for (int n = tc + 1; n <= NNODES; ++n) rowptr[n] = ne;
  }
}

// ---------------- layer kernel: 512 threads / 8 waves, 128 rows, wave-tile 32x64
// all staging via global_load_lds (weights pre-swizzled; gather pre-swizzles src chunk)
template<int L>
__global__ __launch_bounds__(512, 4) void layer_kernel(
    const u16* __restrict__ xb,
    const int* __restrict__ nl,      // (L+2, EL)
    const int* __restrict__ ai,      // (L+2, EL)
    const u16* __restrict__ WtS, const u16* __restrict__ w0S, const u16* __restrict__ w1S,
    const float* __restrict__ eWt,   // (3,3,128) f32
    const float* __restrict__ b0g, const float* __restrict__ b1g,
    const float* __restrict__ cepsg,
    const u16* __restrict__ zrow,
    u16* __restrict__ oL)            // (EL, 128) bf16
{
  constexpr int RPE = (L == 1) ? 2 : 4;
  constexpr int TE  = 128 / RPE;
  constexpr int LI  = L - 1;
  __shared__ __align__(16) u16 sW[CDIM*CDIM];     // 32 KB weights (swizzled via linear DMA)
  __shared__ __align__(16) u16 sA[128*CDIM];      // 32 KB activations (swizzled)
  __shared__ __align__(16) float sE[3*136];
  __shared__ __align__(16) float b0s[CDIM];
  __shared__ __align__(16) float b1s[CDIM];
  __shared__ int sAid[128];

  const int tid  = threadIdx.x;
  const int wave = tid >> 6, lane = tid & 63;
  const int lr   = lane & 15, g = lane >> 4;
  const int wr   = wave >> 1, wc = wave & 1;      // 4 row-groups x 2 col-groups
  const int rowbase  = wr*32;
  const int featbase = wc*64;
  const int e0   = blockIdx.x * TE;
  const int pos  = lr & (RPE - 1);
  const float mu = (pos > 0) ? 1.f : 0.f;
  const float md = (pos < L) ? 1.f : 0.f;
  const float mz = (L == 2 && pos == 3) ? 0.f : 1.f;
  const float ce = 1.0f + cepsg[LI];

  // issue Wt DMA (4 x 1KB per wave, linear src & dest)
  {
    const u16* src = WtS + LI*CDIM*CDIM + wave*4*512 + lane*8;
    u16* dst = sW + wave*4*512;
#pragma unroll
    for (int j = 0; j < 4; ++j) gll16(src + j*512, dst + j*512);
  }
  // issue gather DMA: wave owns rows 16*wave..+15; 4 rows per instruction
#pragma unroll
  for (int i = 0; i < 4; ++i){
    const int r  = wave*16 + 4*i + (lane >> 4);
    const int p  = r & (RPE - 1);
    const int pc = (p <= L) ? p : 0;
    const int node = nl[(1 + pc)*ELEDGES + e0 + r/RPE];
    const u16* src = (p <= L) ? (xb + (size_t)node*CDIM) : zrow;
    const int cl = lane & 15;
    gll16(src + ((cl ^ (r & 7)) << 3), sA + (wave*16 + 4*i)*CDIM);
  }
  // small tables
  for (int c = tid; c < 3*CDIM; c += 512) sE[(c>>7)*136 + (c&127)] = eWt[LI*3*CDIM + c];
  if (tid < CDIM) b0s[tid] = b0g[LI*CDIM + tid];
  else if (tid < 2*CDIM) b1s[tid-CDIM] = b1g[LI*CDIM + (tid-CDIM)];
  if (tid < 128){
    int p = tid & (RPE - 1);
    sAid[tid] = (p <= L) ? ai[(1 + p)*ELEDGES + e0 + tid/RPE] : 0;
  }
  __syncthreads();                                 // B1: vmcnt drain -> sW(Wt)/sA(cc) ready

  f32x4 acc[2][4];
#pragma unroll
  for (int a = 0; a < 2; ++a)
#pragma unroll
    for (int b = 0; b < 4; ++b) acc[a][b] = (f32x4){0.f,0.f,0.f,0.f};
  __builtin_amdgcn_s_setprio(1);
  gemmT(sW, sA, acc, rowbase, featbase, lr, g);    // GEMM1: cc @ Wt_top
  __builtin_amdgcn_s_setprio(0);
  __syncthreads();                                 // B2: all sW/sA reads complete

  // issue w0 DMA (overwrites sW; latency hides under ep1)
  {
    const u16* src = w0S + LI*CDIM*CDIM + wave*4*512 + lane*8;
    u16* dst = sW + wave*4*512;
#pragma unroll
    for (int j = 0; j < 4; ++j) gll16(src + j*512, dst + j*512);
  }
  // ep1: h = acc + eWt[aid]; z = ce*cc + h[row-1] + h[row+1]  (DPP stencil, own tile)
#pragma unroll
  for (int a = 0; a < 2; ++a){
    const int r = rowbase + 16*a + lr;
    const float* eWrow = &sE[sAid[r]*136];
#pragma unroll
    for (int b = 0; b < 4; ++b){
      const int col0 = featbase + 16*b + g*4;
      float4 ew = *(const float4*)&eWrow[col0];
      float h0 = acc[a][b][0] + ew.x;
      float h1 = acc[a][b][1] + ew.y;
      float h2 = acc[a][b][2] + ew.z;
      float h3 = acc[a][b][3] + ew.w;
      float u0 = dppf<DPP_SHR1>(h0), u1 = dppf<DPP_SHR1>(h1),
            u2 = dppf<DPP_SHR1>(h2), u3 = dppf<DPP_SHR1>(h3);
      float d0 = dppf<DPP_SHL1>(h0), d1 = dppf<DPP_SHL1>(h1),
            d2 = dppf<DPP_SHL1>(h2), d3 = dppf<DPP_SHL1>(h3);
      uint2 ccv = *(const uint2*)&sA[swz8(r, col0)];
      float c0 = bf2f(ccv.x & 0xffffu), c1 = bf2f_hi(ccv.x);
      float c2 = bf2f(ccv.y & 0xffffu), c3 = bf2f_hi(ccv.y);
      uint2 zv;
      zv.x = cvtpk(ce*c0 + mu*u0 + md*d0, ce*c1 + mu*u1 + md*d1);
      zv.y = cvtpk(ce*c2 + mu*u2 + md*d2, ce*c3 + mu*u3 + md*d3);
      *(uint2*)&sA[swz8(r, col0)] = zv;
    }
  }
  __syncthreads();                                 // B3: w0 landed + z complete

#pragma unroll
  for (int a = 0; a < 2; ++a)
#pragma unroll
    for (int b = 0; b < 4; ++b) acc[a][b] = (f32x4){0.f,0.f,0.f,0.f};
  __builtin_amdgcn_s_setprio(1);
  gemmT(sW, sA, acc, rowbase, featbase, lr, g);    // GEMM2: z @ w0
  __builtin_amdgcn_s_setprio(0);
  __syncthreads();                                 // B4: all sW/sA reads complete

  // issue w1 DMA
  {
    const u16* src = w1S + LI*CDIM*CDIM + wave*4*512 + lane*8;
    u16* dst = sW + wave*4*512;
#pragma unroll
    for (int j = 0; j < 4; ++j) gll16(src + j*512, dst + j*512);
  }
  // ep2: t = relu(acc + b0) -> own tile
#pragma unroll
  for (int a = 0; a < 2; ++a){
    const int r = rowbase + 16*a + lr;
#pragma unroll
    for (int b = 0; b < 4; ++b){
      const int col0 = featbase + 16*b + g*4;
      float4 bb = *(const float4*)&b0s[col0];
      float t0 = acc[a][b][0] + bb.x; t0 = t0 > 0.f ? t0 : 0.f;
      float t1 = acc[a][b][1] + bb.y; t1 = t1 > 0.f ? t1 : 0.f;
      float t2 = acc[a][b][2] + bb.z; t2 = t2 > 0.f ? t2 : 0.f;
      float t3 = acc[a][b][3] + bb.w; t3 = t3 > 0.f ? t3 : 0.f;
      uint2 tv; tv.x = cvtpk(t0, t1); tv.y = cvtpk(t2, t3);
      *(uint2*)&sA[swz8(r, col0)] = tv;
    }
  }
  __syncthreads();                                 // B5: w1 landed + t complete

#pragma unroll
  for (int a = 0; a < 2; ++a)
#pragma unroll
    for (int b = 0; b < 4; ++b) acc[a][b] = (f32x4){0.f,0.f,0.f,0.f};
  __builtin_amdgcn_s_setprio(1);
  gemmT(sW, sA, acc, rowbase, featbase, lr, g);    // GEMM3: t @ w1
  __builtin_amdgcn_s_setprio(0);

  // ep3: per-edge sum over positions (DPP quad reduce) + (L+1)*b1, store bf16
  const float nb = (float)(L + 1);
#pragma unroll
  for (int a = 0; a < 2; ++a){
    const int r = rowbase + 16*a + lr;
    const int ed = e0 + r/RPE;
#pragma unroll
    for (int b = 0; b < 4; ++b){
      float v0 = mz*acc[a][b][0], v1 = mz*acc[a][b][1],
            v2 = mz*acc[a][b][2], v3 = mz*acc[a][b][3];
      v0 += dppf<DPP_XOR1>(v0); v1 += dppf<DPP_XOR1>(v1);
      v2 += dppf<DPP_XOR1>(v2); v3 += dppf<DPP_XOR1>(v3);
      if constexpr (RPE == 4){
        v0 += dppf<DPP_XOR2>(v0); v1 += dppf<DPP_XOR2>(v1);
        v2 += dppf<DPP_XOR2>(v2); v3 += dppf<DPP_XOR2>(v3);
      }
      if (pos == 0){
        const int col0 = featbase + 16*b + g*4;
        float4 bb = *(const float4*)&b1s[col0];
        uint2 ov;
        ov.x = cvtpk(v0 + nb*bb.x, v1 + nb*bb.y);
        ov.y = cvtpk(v2 + nb*bb.z, v3 + nb*bb.w);
        *(uint2*)(oL + (size_t)ed*CDIM + col0) = ov;
      }
    }
  }
}

// ---------------- per-node gather: rc = (1+r0)*seg0 + sum_L (1+rL)*segL  (bf16 out)
__global__ __launch_bounds__(256) void gather_rc_kernel(
    const float* __restrict__ x, const u16* __restrict__ xbopt,
    const int* __restrict__ s0,
    const int* __restrict__ rp0, const int* __restrict__ rp1,
    const int* __restrict__ rp2, const int* __restrict__ rp3,
    const u16* __restrict__ o1, const u16* __restrict__ o2, const u16* __restrict__ o3,
    const float* __restrict__ repsg, u16* __restrict__ rcb)
{
  const int wave = threadIdx.x >> 6, lane = threadIdx.x & 63;
  const int node = blockIdx.x*4 + wave;
  if (node >= NNODES) return;
  float a0 = 0.f, a1 = 0.f;
  {
    const float sc = 1.f + repsg[0];
    int lo = rp0[node], hi = rp0[node+1];
    if (xbopt){
      for (int e = lo; e < hi; ++e){
        int s = s0[e];
        u32 v = *(const u32*)(xbopt + (size_t)s*CDIM + lane*2);
        a0 += sc*bf2f(v & 0xffffu); a1 += sc*bf2f_hi(v);
      }
    } else {
      for (int e = lo; e < hi; ++e){
        int s = s0[e];
        float2 v = *(const float2*)(x + (size_t)s*CDIM + lane*2);
        a0 += sc*v.x; a1 += sc*v.y;
      }
    }
  }
  const u16* os[3]  = {o1, o2, o3};
  const int* rps[3] = {rp1, rp2, rp3};
#pragma unroll
  for (int li = 0; li < 3; ++li){
    const float sc = 1.f + repsg[1+li];
    int lo = rps[li][node], hi = rps[li][node+1];
    for (int e = lo; e < hi; ++e){
      u32 v = *(const u32*)(os[li] + (size_t)e*CDIM + lane*2);
      a0 += sc*bf2f(v & 0xffffu); a1 += sc*bf2f_hi(v);
    }
  }
  *(u32*)(rcb + (size_t)node*CDIM + lane*2) = pack2(a0, a1);
}

// ---------------- final: out = mlp2((1+eps)*x + rc, fin_*)  (f32 out)
__global__ __launch_bounds__(256) void final_kernel(
    const float* __restrict__ x, const u16* __restrict__ rc,
    const u16* __restrict__ fw0T, const u16* __restrict__ fw1T,
    const float* __restrict__ fb0, const float* __restrict__ fb1,
    const float* __restrict__ epsg, float* __restrict__ outp)
{
  __shared__ __align__(16) u16 sW[CDIM*CDIM];
  __shared__ __align__(16) u16 sA[64*CDIM];
  const int tid  = threadIdx.x;
  const int wave = tid >> 6, lane = tid & 63;
  const int lr   = lane & 15, g = lane >> 4;
  const int r0   = blockIdx.x * 64;
  const float se = 1.0f + epsg[0];

  stage_w(fw0T, sW, tid);
  for (int c = tid; c < 64*16; c += 256){
    int r = c >> 4, ch = c & 15;
    int node = r0 + r;
    uint4 v = make_uint4(0,0,0,0);
    if (node < NNODES){
      const float4* px = (const float4*)(x + (size_t)node*CDIM + ch*8);
      float4 fa = px[0], fb = px[1];
      const u32* pr = (const u32*)(rc + (size_t)node*CDIM + ch*8);
      u32 r0v = pr[0], r1v = pr[1], r2v = pr[2], r3v = pr[3];
      v.x = pack2(se*fa.x + bf2f(r0v & 0xffffu), se*fa.y + bf2f_hi(r0v));
      v.y = pack2(se*fa.z + bf2f(r1v & 0xffffu), se*fa.w + bf2f_hi(r1v));
      v.z = pack2(se*fb.x + bf2f(r2v & 0xffffu), se*fb.y + bf2f_hi(r2v));
      v.w = pack2(se*fb.z + bf2f(r3v & 0xffffu), se*fb.w + bf2f_hi(r3v));
    }
    *(uint4*)&sA[(r*16 + (ch ^ (r & 7)))*8] = v;
  }
  __syncthreads();

  f32x4 acc[8];
#pragma unroll
  for (int ct = 0; ct < 8; ++ct) acc[ct] = (f32x4){0.f,0.f,0.f,0.f};
  gemm64(sA, sW, acc, wave, lane);
  __syncthreads();
#pragma unroll
  for (int ct = 0; ct < 8; ++ct){
    const int col = ct*16 + lr;
    const float bb = fb0[col];
#pragma unroll
    for (int q = 0; q < 4; ++q){
      const int r = wave*16 + g*4 + q;
      float t = acc[ct][q] + bb;
      t = t > 0.f ? t : 0.f;
      sA[swzi(r, col)] = f2bf(t);
    }
  }
  stage_w(fw1T, sW, tid);
  __syncthreads();
#pragma unroll
  for (int ct = 0; ct < 8; ++ct) acc[ct] = (f32x4){0.f,0.f,0.f,0.f};
  gemm64(sA, sW, acc, wave, lane);
#pragma unroll
  for (int ct = 0; ct < 8; ++ct){
    const int col = ct*16 + lr;
    const float bb = fb1[col];
#pragma unroll
    for (int q = 0; q < 4; ++q){
      const int r = wave*16 + g*4 + q;
      int node = r0 + r;
      if (node < NNODES) outp[(size_t)node*CDIM + col] = acc[ct][q] + bb;
    }
  }
}

extern "C" void kernel_launch(void* const* d_in, const int* in_sizes, int n_in,
                              void* d_out, int out_size, void* d_ws, size_t ws_size,
                              hipStream_t stream)
{
  const float* x   = (const float*)d_in[0];
  const int* n0    = (const int*)d_in[1];
  const int* n1    = (const int*)d_in[2];
  const int* a1    = (const int*)d_in[3];
  const int* n2    = (const int*)d_in[4];
  const int* a2    = (const int*)d_in[5];
  const int* n3    = (const int*)d_in[6];
  const int* a3    = (const int*)d_in[7];
  const float* emb = (const float*)d_in[8];
  const float* Wt  = (const float*)d_in[9];
  const float* bt  = (const float*)d_in[10];
  const float* w0  = (const float*)d_in[11];
  const float* b0  = (const float*)d_in[12];
  const float* w1  = (const float*)d_in[13];
  const float* b1  = (const float*)d_in[14];
  const float* ceps= (const float*)d_in[15];
  const float* reps= (const float*)d_in[16];
  const float* eps = (const float*)d_in[17];
  const float* fw0 = (const float*)d_in[18];
  const float* fb0 = (const float*)d_in[19];
  const float* fw1 = (const float*)d_in[20];
  const float* fb1 = (const float*)d_in[21];
  float* outp = (float*)d_out;

  char* w = (char*)d_ws;
  size_t off = 0;
  auto alloc = [&](size_t bytes) -> char* {
    char* p = w + off;
    off += (bytes + 255) & ~((size_t)255);
    return p;
  };
  u16* o1   = (u16*)alloc((size_t)ELEDGES*CDIM*2);
  u16* o2   = (u16*)alloc((size_t)ELEDGES*CDIM*2);
  u16* o3   = (u16*)alloc((size_t)ELEDGES*CDIM*2);
  u16* rcb  = (u16*)alloc((size_t)NNODES*CDIM*2);
  int* rp0  = (int*)alloc((size_t)(NNODES+1)*4);
  int* rp1  = (int*)alloc((size_t)(NNODES+1)*4);
  int* rp2  = (int*)alloc((size_t)(NNODES+1)*4);
  int* rp3  = (int*)alloc((size_t)(NNODES+1)*4);
  u16* WtS  = (u16*)alloc((size_t)3*CDIM*CDIM*2);
  u16* w0S  = (u16*)alloc((size_t)3*CDIM*CDIM*2);
  u16* w1S  = (u16*)alloc((size_t)3*CDIM*CDIM*2);
  u16* fw0T = (u16*)alloc((size_t)CDIM*CDIM*2);
  u16* fw1T = (u16*)alloc((size_t)CDIM*CDIM*2);
  float* eWt = (float*)alloc((size_t)3*3*CDIM*4);
  u16* zrow = (u16*)alloc((size_t)CDIM*2);
  // xb: separate allocation if ws permits (keeps xb alive for gather_rc);
  // else alias rcb (layer kernels consume xb before gather_rc writes rcb).
  const size_t xbbytes = (size_t)NNODES*CDIM*2;
  u16* xb; const u16* xbopt;
  if (off + xbbytes <= ws_size){ xb = (u16*)alloc(xbbytes); xbopt = xb; }
  else { xb = rcb; xbopt = nullptr; }
  (void)in_sizes; (void)n_in; (void)out_size;

  prep_kernel<<<192, 256, 0, stream>>>(Wt, w0, w1, fw0, fw1, emb, bt,
                                       WtS, w0S, w1S, fw0T, fw1T, eWt);
  {
    const int XBQ = NNODES*CDIM/4;
    int total = XBQ + E0EDGES + 3*ELEDGES + 64;
    aux_kernel<<<(total + 255)/256, 256, 0, stream>>>(x, xb, n0, n1, n2, n3,
                                                      rp0, rp1, rp2, rp3, zrow);
  }

  layer_kernel<1><<<ELEDGES/64, 512, 0, stream>>>(xb, n1, a1, WtS, w0S, w1S, eWt, b0, b1, ceps, zrow, o1);
  layer_kernel<2><<<ELEDGES/32, 512, 0, stream>>>(xb, n2, a2, WtS, w0S, w1S, eWt, b0, b1, ceps, zrow, o2);
  layer_kernel<3><<<ELEDGES/32, 512, 0, stream>>>(xb, n3, a3, WtS, w0S, w1S, eWt, b0, b1, ceps, zrow, o3);

  gather_rc_kernel<<<(NNODES+3)/4, 256, 0, stream>>>(x, xbopt, n0 + E0EDGES, rp0, rp1, rp2, rp3,
                                                     o1, o2, o3, reps, rcb);
  final_kernel<<<(NNODES+63)/64, 256, 0, stream>>>(x, rcb, fw0T, fw1T, fb0, fb1, eps, outp);
}

// Round 6
// 362.236 us; speedup vs baseline: 1.4284x; 1.0848x over previous
//
#include <hip/hip_runtime.h>
#include <stdint.h>

#define CDIM 128
#define NNODES 100000
#define E0EDGES 300000
#define ELEDGES 80000

typedef unsigned short u16;
typedef unsigned int u32;
typedef short bf16x8 __attribute__((ext_vector_type(8)));
typedef float f32x4 __attribute__((ext_vector_type(4)));

__device__ __forceinline__ float bf2f(u32 u){
  union { u32 i; float f; } v; v.i = u << 16; return v.f;
}
__device__ __forceinline__ float bf2f_hi(u32 u){
  union { u32 i; float f; } v; v.i = u & 0xffff0000u; return v.f;
}
__device__ __forceinline__ u16 f2bf(float f){
  u32 u = __builtin_bit_cast(u32, f);
  u32 r = (u + 0x7fffu + ((u >> 16) & 1u)) >> 16;
  return (u16)r;
}
__device__ __forceinline__ u32 pack2(float lo, float hi){
  return ((u32)f2bf(hi) << 16) | (u32)f2bf(lo);
}
__device__ __forceinline__ u32 cvtpk(float lo, float hi){
  u32 r;
  asm("v_cvt_pk_bf16_f32 %0, %1, %2" : "=v"(r) : "v"(lo), "v"(hi));
  return r;
}
template<int CTRL>
__device__ __forceinline__ float dppf(float v){
  int r = __builtin_amdgcn_update_dpp(0, __builtin_bit_cast(int, v), CTRL, 0xF, 0xF, true);
  return __builtin_bit_cast(float, r);
}
#define DPP_SHR1 0x111   // lane l <- l-1 (within 16-lane row)
#define DPP_SHL1 0x101   // lane l <- l+1
#define DPP_XOR1 0xB1    // quad_perm [1,0,3,2]
#define DPP_XOR2 0x4E    // quad_perm [2,3,0,1]

// async global->LDS, 16B per lane, linear LDS dest (base + lane*16)
__device__ __forceinline__ void gll16(const void* g, void* l){
  __builtin_amdgcn_global_load_lds(
      (const __attribute__((address_space(1))) void*)g,
      (__attribute__((address_space(3))) void*)l, 16, 0, 0);
}

// element index of swizzled [rows][128] bf16 LDS tile (16B-granule XOR swizzle)
__device__ __forceinline__ int swzi(int r, int c){
  return r*CDIM + ((((c>>3) ^ (r&7)))<<3) + (c&7);
}
// index of a 4-col group (col0 multiple of 4, stays within one 8-col granule)
__device__ __forceinline__ int swz8(int r, int col0){
  int chunk = col0 >> 3;
  return r*CDIM + ((chunk ^ (r & 7)) << 3) + (col0 & 7);
}

// ---- 32x64 register-tiled gemm (validated R5)
__device__ __forceinline__ void gemmT(const u16* W, const u16* A, f32x4 acc[2][4],
                                      int rowbase, int featbase, int lr, int g){
#pragma unroll
  for (int ks = 0; ks < 4; ++ks){
    const int sch = ((ks*4 + g) ^ (lr & 7)) << 3;
    bf16x8 a0 = *(const bf16x8*)&A[(rowbase      + lr)*CDIM + sch];
    bf16x8 a1 = *(const bf16x8*)&A[(rowbase + 16 + lr)*CDIM + sch];
    bf16x8 w0f = *(const bf16x8*)&W[(featbase      + lr)*CDIM + sch];
    bf16x8 w1f = *(const bf16x8*)&W[(featbase + 16 + lr)*CDIM + sch];
    bf16x8 w2f = *(const bf16x8*)&W[(featbase + 32 + lr)*CDIM + sch];
    bf16x8 w3f = *(const bf16x8*)&W[(featbase + 48 + lr)*CDIM + sch];
    acc[0][0] = __builtin_amdgcn_mfma_f32_16x16x32_bf16(w0f, a0, acc[0][0], 0, 0, 0);
    acc[0][1] = __builtin_amdgcn_mfma_f32_16x16x32_bf16(w1f, a0, acc[0][1], 0, 0, 0);
    acc[0][2] = __builtin_amdgcn_mfma_f32_16x16x32_bf16(w2f, a0, acc[0][2], 0, 0, 0);
    acc[0][3] = __builtin_amdgcn_mfma_f32_16x16x32_bf16(w3f, a0, acc[0][3], 0, 0, 0);
    acc[1][0] = __builtin_amdgcn_mfma_f32_16x16x32_bf16(w0f, a1, acc[1][0], 0, 0, 0);
    acc[1][1] = __builtin_amdgcn_mfma_f32_16x16x32_bf16(w1f, a1, acc[1][1], 0, 0, 0);
    acc[1][2] = __builtin_amdgcn_mfma_f32_16x16x32_bf16(w2f, a1, acc[1][2], 0, 0, 0);
    acc[1][3] = __builtin_amdgcn_mfma_f32_16x16x32_bf16(w3f, a1, acc[1][3], 0, 0, 0);
  }
}

// ---- legacy 16-row gemm (final_kernel): acc(row = g*4+q, col = ct*16+lr)
__device__ __forceinline__ void gemm64(const u16* A, const u16* B, f32x4* acc, int wave, int lane){
  const int lr = lane & 15, g = lane >> 4;
  const int arow = wave*16 + lr;
#pragma unroll
  for (int ks = 0; ks < 4; ++ks){
    const int ach = ks*4 + g;
    bf16x8 a = *(const bf16x8*)&A[arow*CDIM + ((ach ^ (arow & 7)) << 3)];
#pragma unroll
    for (int ct = 0; ct < 8; ++ct){
      const int brow = ct*16 + lr;
      bf16x8 b = *(const bf16x8*)&B[brow*CDIM + ((ach ^ (brow & 7)) << 3)];
      acc[ct] = __builtin_amdgcn_mfma_f32_16x16x32_bf16(a, b, acc[ct], 0, 0, 0);
    }
  }
}

__device__ __forceinline__ void stage_w(const u16* __restrict__ gsrc, u16* sdst, int tid){
  for (int c = tid; c < CDIM*16; c += 256){
    int r = c >> 4, ch = c & 15;
    *(uint4*)&sdst[(r*16 + (ch ^ (r & 7)))*8] = ((const uint4*)(gsrc + r*CDIM))[ch];
  }
}

// ---------------- prep_aux (merged): xb, CSR x4, weight swizzles, fw transposes, eWt, zrow
__global__ __launch_bounds__(256) void prep_aux_kernel(
    const float* __restrict__ x, u16* __restrict__ xb,
    const int* __restrict__ n0, const int* __restrict__ n1,
    const int* __restrict__ n2, const int* __restrict__ n3,
    int* __restrict__ rp0, int* __restrict__ rp1,
    int* __restrict__ rp2, int* __restrict__ rp3,
    const float* __restrict__ Wt, const float* __restrict__ w0, const float* __restrict__ w1,
    const float* __restrict__ fw0, const float* __restrict__ fw1,
    const float* __restrict__ emb, const float* __restrict__ bt,
    u16* __restrict__ WtS, u16* __restrict__ w0S, u16* __restrict__ w1S,
    u16* __restrict__ fw0T, u16* __restrict__ fw1T, float* __restrict__ eWt,
    u16* __restrict__ zrow)
{
  const int XBQ  = NNODES*CDIM/4;
  const int NCSR = E0EDGES + 3*ELEDGES;
  const int NW   = 3*CDIM*CDIM;
  const int NF   = CDIM*CDIM;
  const int NE   = 3*3*CDIM;
  int t = blockIdx.x*256 + threadIdx.x;
  if (t < XBQ){
    size_t idx = (size_t)t*4;
    float4 v = *(const float4*)(x + idx);
    uint2 o; o.x = cvtpk(v.x, v.y); o.y = cvtpk(v.z, v.w);
    *(uint2*)(xb + idx) = o;
    return;
  }
  t -= XBQ;
  if (t < NCSR){
    const int* tgt; int ne; int* rowptr;
    if (t < E0EDGES){ tgt = n0; ne = E0EDGES; rowptr = rp0; }
    else { t -= E0EDGES;
      if (t < ELEDGES){ tgt = n1; ne = ELEDGES; rowptr = rp1; }
      else { t -= ELEDGES;
        if (t < ELEDGES){ tgt = n2; ne = ELEDGES; rowptr = rp2; }
        else { t -= ELEDGES; tgt = n3; ne = ELEDGES; rowptr = rp3; }
      }
    }
    int e = t;
    int tc = tgt[e];
    int tp = (e == 0) ? -1 : tgt[e-1];
    for (int n = tp + 1; n <= tc; ++n) rowptr[n] = e;
    if (e == ne - 1){
      for (int n = tc + 1; n <= NNODES; ++n) rowptr[n] = ne;
    }
    return;
  }
  t -= NCSR;
  if (t < NW){
    // swizzled store: halfword s -> W^T[r][k], r=s>>7, ch=((s>>3)&15)^(r&7), k=ch*8+(s&7)
    int i = t >> 14, s = t & 16383;
    int r = s >> 7, ch = ((s >> 3) & 15) ^ (r & 7), k = ch*8 + (s & 7);
    WtS[t] = f2bf(Wt[(size_t)i*2*CDIM*CDIM + k*CDIM + r]);
    w0S[t] = f2bf(w0[(size_t)i*CDIM*CDIM + k*CDIM + r]);
    w1S[t] = f2bf(w1[(size_t)i*CDIM*CDIM + k*CDIM + r]);
    return;
  }
  t -= NW;
  if (t < NF){
    int col = t/CDIM, k = t%CDIM;
    fw0T[t] = f2bf(fw0[k*CDIM + col]);
    fw1T[t] = f2bf(fw1[k*CDIM + col]);
    return;
  }
  t -= NF;
  if (t < NE){
    int i = t/(3*CDIM), a = (t/CDIM)%3, c2 = t%CDIM;
    float s = bt[i*CDIM + c2];
    for (int k = 0; k < CDIM; ++k)
      s += emb[(i*3 + a)*CDIM + k] * Wt[(size_t)i*2*CDIM*CDIM + (CDIM + k)*CDIM + c2];
    eWt[t] = s;
    return;
  }
  t -= NE;
  if (t < 64) ((u32*)zrow)[t] = 0u;
}

// ---------------- layer body (templated, unchanged logic from R5) ----------------
template<int L>
__device__ __forceinline__ void layer_body(
    int bidx,
    const u16* __restrict__ xb,
    const int* __restrict__ nl, const int* __restrict__ ai,
    const u16* __restrict__ WtS, const u16* __restrict__ w0S, const u16* __restrict__ w1S,
    const float* __restrict__ eWt,
    const float* __restrict__ b0g, const float* __restrict__ b1g,
    const float* __restrict__ cepsg,
    const u16* __restrict__ zrow,
    u16* __restrict__ oL,
    u16* sW, u16* sA, float* sE, float* b0s, float* b1s, int* sAid)
{
  constexpr int RPE = (L == 1) ? 2 : 4;
  constexpr int TE  = 128 / RPE;
  constexpr int LI  = L - 1;

  const int tid  = threadIdx.x;
  const int wave = tid >> 6, lane = tid & 63;
  const int lr   = lane & 15, g = lane >> 4;
  const int wr   = wave >> 1, wc = wave & 1;
  const int rowbase  = wr*32;
  const int featbase = wc*64;
  const int e0   = bidx * TE;
  const int pos  = lr & (RPE - 1);
  const float mu = (pos > 0) ? 1.f : 0.f;
  const float md = (pos < L) ? 1.f : 0.f;
  const float mz = (L == 2 && pos == 3) ? 0.f : 1.f;
  const float ce = 1.0f + cepsg[LI];

  // issue Wt DMA
  {
    const u16* src = WtS + LI*CDIM*CDIM + wave*4*512 + lane*8;
    u16* dst = sW + wave*4*512;
#pragma unroll
    for (int j = 0; j < 4; ++j) gll16(src + j*512, dst + j*512);
  }
  // issue gather DMA: wave owns rows 16*wave..+15; 4 rows per instruction
#pragma unroll
  for (int i = 0; i < 4; ++i){
    const int r  = wave*16 + 4*i + (lane >> 4);
    const int p  = r & (RPE - 1);
    const int pc = (p <= L) ? p : 0;
    const int node = nl[(1 + pc)*ELEDGES + e0 + r/RPE];
    const u16* src = (p <= L) ? (xb + (size_t)node*CDIM) : zrow;
    const int cl = lane & 15;
    gll16(src + ((cl ^ (r & 7)) << 3), sA + (wave*16 + 4*i)*CDIM);
  }
  for (int c = tid; c < 3*CDIM; c += 512) sE[(c>>7)*136 + (c&127)] = eWt[LI*3*CDIM + c];
  if (tid < CDIM) b0s[tid] = b0g[LI*CDIM + tid];
  else if (tid < 2*CDIM) b1s[tid-CDIM] = b1g[LI*CDIM + (tid-CDIM)];
  if (tid < 128){
    int p = tid & (RPE - 1);
    sAid[tid] = (p <= L) ? ai[(1 + p)*ELEDGES + e0 + tid/RPE] : 0;
  }
  __syncthreads();                                 // B1

  f32x4 acc[2][4];
#pragma unroll
  for (int a = 0; a < 2; ++a)
#pragma unroll
    for (int b = 0; b < 4; ++b) acc[a][b] = (f32x4){0.f,0.f,0.f,0.f};
  __builtin_amdgcn_s_setprio(1);
  gemmT(sW, sA, acc, rowbase, featbase, lr, g);    // GEMM1
  __builtin_amdgcn_s_setprio(0);
  __syncthreads();                                 // B2

  {
    const u16* src = w0S + LI*CDIM*CDIM + wave*4*512 + lane*8;
    u16* dst = sW + wave*4*512;
#pragma unroll
    for (int j = 0; j < 4; ++j) gll16(src + j*512, dst + j*512);
  }
#pragma unroll
  for (int a = 0; a < 2; ++a){
    const int r = rowbase + 16*a + lr;
    const float* eWrow = &sE[sAid[r]*136];
#pragma unroll
    for (int b = 0; b < 4; ++b){
      const int col0 = featbase + 16*b + g*4;
      float4 ew = *(const float4*)&eWrow[col0];
      float h0 = acc[a][b][0] + ew.x;
      float h1 = acc[a][b][1] + ew.y;
      float h2 = acc[a][b][2] + ew.z;
      float h3 = acc[a][b][3] + ew.w;
      float u0 = dppf<DPP_SHR1>(h0), u1 = dppf<DPP_SHR1>(h1),
            u2 = dppf<DPP_SHR1>(h2), u3 = dppf<DPP_SHR1>(h3);
      float d0 = dppf<DPP_SHL1>(h0), d1 = dppf<DPP_SHL1>(h1),
            d2 = dppf<DPP_SHL1>(h2), d3 = dppf<DPP_SHL1>(h3);
      uint2 ccv = *(const uint2*)&sA[swz8(r, col0)];
      float c0 = bf2f(ccv.x & 0xffffu), c1 = bf2f_hi(ccv.x);
      float c2 = bf2f(ccv.y & 0xffffu), c3 = bf2f_hi(ccv.y);
      uint2 zv;
      zv.x = cvtpk(ce*c0 + mu*u0 + md*d0, ce*c1 + mu*u1 + md*d1);
      zv.y = cvtpk(ce*c2 + mu*u2 + md*d2, ce*c3 + mu*u3 + md*d3);
      *(uint2*)&sA[swz8(r, col0)] = zv;
    }
  }
  __syncthreads();                                 // B3

#pragma unroll
  for (int a = 0; a < 2; ++a)
#pragma unroll
    for (int b = 0; b < 4; ++b) acc[a][b] = (f32x4){0.f,0.f,0.f,0.f};
  __builtin_amdgcn_s_setprio(1);
  gemmT(sW, sA, acc, rowbase, featbase, lr, g);    // GEMM2
  __builtin_amdgcn_s_setprio(0);
  __syncthreads();                                 // B4

  {
    const u16* src = w1S + LI*CDIM*CDIM + wave*4*512 + lane*8;
    u16* dst = sW + wave*4*512;
#pragma unroll
    for (int j = 0; j < 4; ++j) gll16(src + j*512, dst + j*512);
  }
#pragma unroll
  for (int a = 0; a < 2; ++a){
    const int r = rowbase + 16*a + lr;
#pragma unroll
    for (int b = 0; b < 4; ++b){
      const int col0 = featbase + 16*b + g*4;
      float4 bb = *(const float4*)&b0s[col0];
      float t0 = acc[a][b][0] + bb.x; t0 = t0 > 0.f ? t0 : 0.f;
      float t1 = acc[a][b][1] + bb.y; t1 = t1 > 0.f ? t1 : 0.f;
      float t2 = acc[a][b][2] + bb.z; t2 = t2 > 0.f ? t2 : 0.f;
      float t3 = acc[a][b][3] + bb.w; t3 = t3 > 0.f ? t3 : 0.f;
      uint2 tv; tv.x = cvtpk(t0, t1); tv.y = cvtpk(t2, t3);
      *(uint2*)&sA[swz8(r, col0)] = tv;
    }
  }
  __syncthreads();                                 // B5

#pragma unroll
  for (int a = 0; a < 2; ++a)
#pragma unroll
    for (int b = 0; b < 4; ++b) acc[a][b] = (f32x4){0.f,0.f,0.f,0.f};
  __builtin_amdgcn_s_setprio(1);
  gemmT(sW, sA, acc, rowbase, featbase, lr, g);    // GEMM3
  __builtin_amdgcn_s_setprio(0);

  const float nb = (float)(L + 1);
#pragma unroll
  for (int a = 0; a < 2; ++a){
    const int r = rowbase + 16*a + lr;
    const int ed = e0 + r/RPE;
#pragma unroll
    for (int b = 0; b < 4; ++b){
      float v0 = mz*acc[a][b][0], v1 = mz*acc[a][b][1],
            v2 = mz*acc[a][b][2], v3 = mz*acc[a][b][3];
      v0 += dppf<DPP_XOR1>(v0); v1 += dppf<DPP_XOR1>(v1);
      v2 += dppf<DPP_XOR1>(v2); v3 += dppf<DPP_XOR1>(v3);
      if constexpr (RPE == 4){
        v0 += dppf<DPP_XOR2>(v0); v1 += dppf<DPP_XOR2>(v1);
        v2 += dppf<DPP_XOR2>(v2); v3 += dppf<DPP_XOR2>(v3);
      }
      if (pos == 0){
        const int col0 = featbase + 16*b + g*4;
        float4 bb = *(const float4*)&b1s[col0];
        uint2 ov;
        ov.x = cvtpk(v0 + nb*bb.x, v1 + nb*bb.y);
        ov.y = cvtpk(v2 + nb*bb.z, v3 + nb*bb.w);
        *(uint2*)(oL + (size_t)ed*CDIM + col0) = ov;
      }
    }
  }
}

// ---------------- merged layers kernel: blockIdx range -> layer
__global__ __launch_bounds__(512, 4) void layers_kernel(
    const u16* __restrict__ xb,
    const int* __restrict__ n1, const int* __restrict__ a1,
    const int* __restrict__ n2, const int* __restrict__ a2,
    const int* __restrict__ n3, const int* __restrict__ a3,
    const u16* __restrict__ WtS, const u16* __restrict__ w0S, const u16* __restrict__ w1S,
    const float* __restrict__ eWt,
    const float* __restrict__ b0g, const float* __restrict__ b1g,
    const float* __restrict__ cepsg,
    const u16* __restrict__ zrow,
    u16* __restrict__ o1, u16* __restrict__ o2, u16* __restrict__ o3)
{
  __shared__ __align__(16) u16 sW[CDIM*CDIM];
  __shared__ __align__(16) u16 sA[128*CDIM];
  __shared__ __align__(16) float sE[3*136];
  __shared__ __align__(16) float b0s[CDIM];
  __shared__ __align__(16) float b1s[CDIM];
  __shared__ int sAid[128];
  constexpr int NB1 = ELEDGES/64;   // 1250
  constexpr int NB2 = ELEDGES/32;   // 2500
  const int b = blockIdx.x;
  if (b < NB1)
    layer_body<1>(b, xb, n1, a1, WtS, w0S, w1S, eWt, b0g, b1g, cepsg, zrow, o1,
                  sW, sA, sE, b0s, b1s, sAid);
  else if (b < NB1 + NB2)
    layer_body<2>(b - NB1, xb, n2, a2, WtS, w0S, w1S, eWt, b0g, b1g, cepsg, zrow, o2,
                  sW, sA, sE, b0s, b1s, sAid);
  else
    layer_body<3>(b - NB1 - NB2, xb, n3, a3, WtS, w0S, w1S, eWt, b0g, b1g, cepsg, zrow, o3,
                  sW, sA, sE, b0s, b1s, sAid);
}

// ---------------- per-node gather: 4 edge-slots x 16 lanes, uint4 rows, shfl reduce
__global__ __launch_bounds__(256) void gather_rc_kernel(
    const float* __restrict__ x, const u16* __restrict__ xbopt,
    const int* __restrict__ s0,
    const int* __restrict__ rp0, const int* __restrict__ rp1,
    const int* __restrict__ rp2, const int* __restrict__ rp3,
    const u16* __restrict__ o1, const u16* __restrict__ o2, const u16* __restrict__ o3,
    const float* __restrict__ repsg, u16* __restrict__ rcb)
{
  const int wave = threadIdx.x >> 6, lane = threadIdx.x & 63;
  const int node = blockIdx.x*4 + wave;
  if (node >= NNODES) return;
  if (xbopt){
    const int lr = lane & 15, gg = lane >> 4;
    float a0=0.f,a1=0.f,a2=0.f,a3=0.f,a4=0.f,a5=0.f,a6=0.f,a7=0.f;
    {
      const float sc = 1.f + repsg[0];
      const int lo = rp0[node], hi = rp0[node+1];
      for (int e = lo + gg; e < hi; e += 4){
        int s = s0[e];
        uint4 v = *(const uint4*)(xbopt + (size_t)s*CDIM + lr*8);
        a0 = fmaf(sc, bf2f(v.x & 0xffffu), a0); a1 = fmaf(sc, bf2f_hi(v.x), a1);
        a2 = fmaf(sc, bf2f(v.y & 0xffffu), a2); a3 = fmaf(sc, bf2f_hi(v.y), a3);
        a4 = fmaf(sc, bf2f(v.z & 0xffffu), a4); a5 = fmaf(sc, bf2f_hi(v.z), a5);
        a6 = fmaf(sc, bf2f(v.w & 0xffffu), a6); a7 = fmaf(sc, bf2f_hi(v.w), a7);
      }
    }
    const u16* os[3]  = {o1, o2, o3};
    const int* rps[3] = {rp1, rp2, rp3};
#pragma unroll
    for (int li = 0; li < 3; ++li){
      const float sc = 1.f + repsg[1+li];
      const int lo = rps[li][node], hi = rps[li][node+1];
      const u16* ob = os[li];
      for (int e = lo + gg; e < hi; e += 4){
        uint4 v = *(const uint4*)(ob + (size_t)e*CDIM + lr*8);
        a0 = fmaf(sc, bf2f(v.x & 0xffffu), a0); a1 = fmaf(sc, bf2f_hi(v.x), a1);
        a2 = fmaf(sc, bf2f(v.y & 0xffffu), a2); a3 = fmaf(sc, bf2f_hi(v.y), a3);
        a4 = fmaf(sc, bf2f(v.z & 0xffffu), a4); a5 = fmaf(sc, bf2f_hi(v.z), a5);
        a6 = fmaf(sc, bf2f(v.w & 0xffffu), a6); a7 = fmaf(sc, bf2f_hi(v.w), a7);
      }
    }
    // reduce across the 4 edge-slot groups (lanes lr, lr+16, lr+32, lr+48)
    a0 += __shfl_xor(a0, 16, 64); a1 += __shfl_xor(a1, 16, 64);
    a2 += __shfl_xor(a2, 16, 64); a3 += __shfl_xor(a3, 16, 64);
    a4 += __shfl_xor(a4, 16, 64); a5 += __shfl_xor(a5, 16, 64);
    a6 += __shfl_xor(a6, 16, 64); a7 += __shfl_xor(a7, 16, 64);
    a0 += __shfl_xor(a0, 32, 64); a1 += __shfl_xor(a1, 32, 64);
    a2 += __shfl_xor(a2, 32, 64); a3 += __shfl_xor(a3, 32, 64);
    a4 += __shfl_xor(a4, 32, 64); a5 += __shfl_xor(a5, 32, 64);
    a6 += __shfl_xor(a6, 32, 64); a7 += __shfl_xor(a7, 32, 64);
    if (gg == 0){
      uint4 ov;
      ov.x = cvtpk(a0, a1); ov.y = cvtpk(a2, a3);
      ov.z = cvtpk(a4, a5); ov.w = cvtpk(a6, a7);
      *(uint4*)(rcb + (size_t)node*CDIM + lr*8) = ov;
    }
  } else {
    // fallback scalar path (f32 x), ws-constrained case
    float a0 = 0.f, a1 = 0.f;
    {
      const float sc = 1.f + repsg[0];
      int lo = rp0[node], hi = rp0[node+1];
      for (int e = lo; e < hi; ++e){
        int s = s0[e];
        float2 v = *(const float2*)(x + (size_t)s*CDIM + lane*2);
        a0 += sc*v.x; a1 += sc*v.y;
      }
    }
    const u16* os[3]  = {o1, o2, o3};
    const int* rps[3] = {rp1, rp2, rp3};
#pragma unroll
    for (int li = 0; li < 3; ++li){
      const float sc = 1.f + repsg[1+li];
      int lo = rps[li][node], hi = rps[li][node+1];
      for (int e = lo; e < hi; ++e){
        u32 v = *(const u32*)(os[li] + (size_t)e*CDIM + lane*2);
        a0 += sc*bf2f(v & 0xffffu); a1 += sc*bf2f_hi(v);
      }
    }
    *(u32*)(rcb + (size_t)node*CDIM + lane*2) = pack2(a0, a1);
  }
}

// ---------------- final: out = mlp2((1+eps)*x + rc, fin_*)  (f32 out)
__global__ __launch_bounds__(256) void final_kernel(
    const float* __restrict__ x, const u16* __restrict__ xbopt,
    const u16* __restrict__ rc,
    const u16* __restrict__ fw0T, const u16* __restrict__ fw1T,
    const float* __restrict__ fb0, const float* __restrict__ fb1,
    const float* __restrict__ epsg, float* __restrict__ outp)
{
  __shared__ __align__(16) u16 sW[CDIM*CDIM];
  __shared__ __align__(16) u16 sA[64*CDIM];
  const int tid  = threadIdx.x;
  const int wave = tid >> 6, lane = tid & 63;
  const int lr   = lane & 15, g = lane >> 4;
  const int r0   = blockIdx.x * 64;
  const float se = 1.0f + epsg[0];

  stage_w(fw0T, sW, tid);
  for (int c = tid; c < 64*16; c += 256){
    int r = c >> 4, ch = c & 15;
    int node = r0 + r;
    uint4 v = make_uint4(0,0,0,0);
    if (node < NNODES){
      const u32* pr = (const u32*)(rc + (size_t)node*CDIM + ch*8);
      u32 r0v = pr[0], r1v = pr[1], r2v = pr[2], r3v = pr[3];
      if (xbopt){
        uint4 xv = *(const uint4*)(xbopt + (size_t)node*CDIM + ch*8);
        v.x = cvtpk(se*bf2f(xv.x & 0xffffu) + bf2f(r0v & 0xffffu), se*bf2f_hi(xv.x) + bf2f_hi(r0v));
        v.y = cvtpk(se*bf2f(xv.y & 0xffffu) + bf2f(r1v & 0xffffu), se*bf2f_hi(xv.y) + bf2f_hi(r1v));
        v.z = cvtpk(se*bf2f(xv.z & 0xffffu) + bf2f(r2v & 0xffffu), se*bf2f_hi(xv.z) + bf2f_hi(r2v));
        v.w = cvtpk(se*bf2f(xv.w & 0xffffu) + bf2f(r3v & 0xffffu), se*bf2f_hi(xv.w) + bf2f_hi(r3v));
      } else {
        const float4* px = (const float4*)(x + (size_t)node*CDIM + ch*8);
        float4 fa = px[0], fb = px[1];
        v.x = pack2(se*fa.x + bf2f(r0v & 0xffffu), se*fa.y + bf2f_hi(r0v));
        v.y = pack2(se*fa.z + bf2f(r1v & 0xffffu), se*fa.w + bf2f_hi(r1v));
        v.z = pack2(se*fb.x + bf2f(r2v & 0xffffu), se*fb.y + bf2f_hi(r2v));
        v.w = pack2(se*fb.z + bf2f(r3v & 0xffffu), se*fb.w + bf2f_hi(r3v));
      }
    }
    *(uint4*)&sA[(r*16 + (ch ^ (r & 7)))*8] = v;
  }
  __syncthreads();

  f32x4 acc[8];
#pragma unroll
  for (int ct = 0; ct < 8; ++ct) acc[ct] = (f32x4){0.f,0.f,0.f,0.f};
  gemm64(sA, sW, acc, wave, lane);
  __syncthreads();
#pragma unroll
  for (int ct = 0; ct < 8; ++ct){
    const int col = ct*16 + lr;
    const float bb = fb0[col];
#pragma unroll
    for (int q = 0; q < 4; ++q){
      const int r = wave*16 + g*4 + q;
      float t = acc[ct][q] + bb;
      t = t > 0.f ? t : 0.f;
      sA[swzi(r, col)] = f2bf(t);
    }
  }
  stage_w(fw1T, sW, tid);
  __syncthreads();
#pragma unroll
  for (int ct = 0; ct < 8; ++ct) acc[ct] = (f32x4){0.f,0.f,0.f,0.f};
  gemm64(sA, sW, acc, wave, lane);
#pragma unroll
  for (int ct = 0; ct < 8; ++ct){
    const int col = ct*16 + lr;
    const float bb = fb1[col];
#pragma unroll
    for (int q = 0; q < 4; ++q){
      const int r = wave*16 + g*4 + q;
      int node = r0 + r;
      if (node < NNODES) outp[(size_t)node*CDIM + col] = acc[ct][q] + bb;
    }
  }
}

extern "C" void kernel_launch(void* const* d_in, const int* in_sizes, int n_in,
                              void* d_out, int out_size, void* d_ws, size_t ws_size,
                              hipStream_t stream)
{
  const float* x   = (const float*)d_in[0];
  const int* n0    = (const int*)d_in[1];
  const int* n1    = (const int*)d_in[2];
  const int* a1    = (const int*)d_in[3];
  const int* n2    = (const int*)d_in[4];
  const int* a2    = (const int*)d_in[5];
  const int* n3    = (const int*)d_in[6];
  const int* a3    = (const int*)d_in[7];
  const float* emb = (const float*)d_in[8];
  const float* Wt  = (const float*)d_in[9];
  const float* bt  = (const float*)d_in[10];
  const float* w0  = (const float*)d_in[11];
  const float* b0  = (const float*)d_in[12];
  const float* w1  = (const float*)d_in[13];
  const float* b1  = (const float*)d_in[14];
  const float* ceps= (const float*)d_in[15];
  const float* reps= (const float*)d_in[16];
  const float* eps = (const float*)d_in[17];
  const float* fw0 = (const float*)d_in[18];
  const float* fb0 = (const float*)d_in[19];
  const float* fw1 = (const float*)d_in[20];
  const float* fb1 = (const float*)d_in[21];
  float* outp = (float*)d_out;

  char* w = (char*)d_ws;
  size_t off = 0;
  auto alloc = [&](size_t bytes) -> char* {
    char* p = w + off;
    off += (bytes + 255) & ~((size_t)255);
    return p;
  };
  u16* o1   = (u16*)alloc((size_t)ELEDGES*CDIM*2);
  u16* o2   = (u16*)alloc((size_t)ELEDGES*CDIM*2);
  u16* o3   = (u16*)alloc((size_t)ELEDGES*CDIM*2);
  u16* rcb  = (u16*)alloc((size_t)NNODES*CDIM*2);
  int* rp0  = (int*)alloc((size_t)(NNODES+1)*4);
  int* rp1  = (int*)alloc((size_t)(NNODES+1)*4);
  int* rp2  = (int*)alloc((size_t)(NNODES+1)*4);
  int* rp3  = (int*)alloc((size_t)(NNODES+1)*4);
  u16* WtS  = (u16*)alloc((size_t)3*CDIM*CDIM*2);
  u16* w0S  = (u16*)alloc((size_t)3*CDIM*CDIM*2);
  u16* w1S  = (u16*)alloc((size_t)3*CDIM*CDIM*2);
  u16* fw0T = (u16*)alloc((size_t)CDIM*CDIM*2);
  u16* fw1T = (u16*)alloc((size_t)CDIM*CDIM*2);
  float* eWt = (float*)alloc((size_t)3*3*CDIM*4);
  u16* zrow = (u16*)alloc((size_t)CDIM*2);
  const size_t xbbytes = (size_t)NNODES*CDIM*2;
  u16* xb; const u16* xbopt;
  if (off + xbbytes <= ws_size){ xb = (u16*)alloc(xbbytes); xbopt = xb; }
  else { xb = rcb; xbopt = nullptr; }
  (void)in_sizes; (void)n_in; (void)out_size;

  {
    const int XBQ = NNODES*CDIM/4;
    int total = XBQ + (E0EDGES + 3*ELEDGES) + 3*CDIM*CDIM + CDIM*CDIM + 3*3*CDIM + 64;
    prep_aux_kernel<<<(total + 255)/256, 256, 0, stream>>>(
        x, xb, n0, n1, n2, n3, rp0, rp1, rp2, rp3,
        Wt, w0, w1, fw0, fw1, emb, bt,
        WtS, w0S, w1S, fw0T, fw1T, eWt, zrow);
  }

  layers_kernel<<<ELEDGES/64 + 2*(ELEDGES/32), 512, 0, stream>>>(
      xb, n1, a1, n2, a2, n3, a3, WtS, w0S, w1S, eWt, b0, b1, ceps, zrow, o1, o2, o3);

  gather_rc_kernel<<<(NNODES+3)/4, 256, 0, stream>>>(x, xbopt, n0 + E0EDGES, rp0, rp1, rp2, rp3,
                                                     o1, o2, o3, reps, rcb);
  final_kernel<<<(NNODES+63)/64, 256, 0, stream>>>(x, xbopt, rcb, fw0T, fw1T, fb0, fb1, eps, outp);
}